// Round 1
// baseline (1323.362 us; speedup 1.0000x reference)
//
#include <hip/hip_runtime.h>
#include <math.h>

// Problem constants (from reference):
//   B=16, W=256 -> BW=4096 positions; D=64 pairs/position
//   E=32 embed, CK=2E+1=65 combined, H=256 hidden, H4=64 attn-hidden
#define BW 4096
#define DD 64
#define EE 32
#define CK 65
#define HH 256
#define H4 64
#define PADROW 68   // row stride in floats; 68*4=272 bytes, 16B-aligned for b128

__device__ __forceinline__ float gelu_exact(float x) {
    return 0.5f * x * (1.0f + erff(x * 0.70710678118654752f));
}

__global__ __launch_bounds__(256, 1)
void dist_attn_kernel(const int*   __restrict__ a1,
                      const int*   __restrict__ a2,
                      const float* __restrict__ dist,
                      const int*   __restrict__ mask,
                      const float* __restrict__ table,   // [101][32]
                      const float* __restrict__ w_in,    // [65][256]
                      const float* __restrict__ b_in,    // [256]
                      const float* __restrict__ w_a1,    // [256][64]
                      const float* __restrict__ b_a1,    // [64]
                      const float* __restrict__ w_a2,    // [64]
                      const float* __restrict__ b_a2,    // [1]
                      const float* __restrict__ w_v1,    // [256][256]
                      const float* __restrict__ b_v1,    // [256]
                      const float* __restrict__ w_v2,    // [256][256]
                      const float* __restrict__ b_v2,    // [256]
                      const float* __restrict__ fb,      // [256]
                      float*       __restrict__ out)     // [4096][256]
{
    __shared__ float combT[CK][PADROW];   // [k][d]
    __shared__ float hidT[HH][PADROW];    // [h][d]  (gelu'd hidden, transposed)
    __shared__ float score_s[DD];
    __shared__ float attn_s[DD];
    __shared__ float r_s[HH];
    __shared__ int   anyv_s;

    const int tid  = threadIdx.x;
    const int lane = tid & 63;
    const int wv   = tid >> 6;              // wave id 0..3
    const int blk  = blockIdx.x;            // (b,w) flat index
    const long base = (long)blk * DD;

    // ---------- Phase 0: build combT[k][d] = [e1 | e2 | dist*mask] ----------
    {
        const int d  = tid & 63;
        const int k0 = tid >> 6;            // 0..3
        const int i1 = a1[base + d];
        const int i2 = a2[base + d];
        const int m  = mask[base + d];
        const float dm = dist[base + d] * (float)m;
        for (int k = k0; k < CK; k += 4) {
            float v;
            if (k < EE)          v = (i1 < 100) ? table[i1 * EE + k]        : 0.0f;
            else if (k < 2 * EE) v = (i2 < 100) ? table[i2 * EE + (k - EE)] : 0.0f;
            else                 v = dm;
            combT[k][d] = v;
        }
    }
    __syncthreads();

    // ---------- Phase 1: hidden = gelu(combined @ w_in + b_in) ----------
    // thread h=tid accumulates hidden[d][h] for all 64 d in registers.
    {
        float acc[DD];
        #pragma unroll
        for (int d = 0; d < DD; ++d) acc[d] = 0.0f;
        const int h = tid;
        for (int k = 0; k < CK; ++k) {
            const float w = w_in[k * HH + h];
            const float4* cp = (const float4*)&combT[k][0];
            #pragma unroll
            for (int q = 0; q < 16; ++q) {
                const float4 c = cp[q];
                acc[4 * q + 0] += c.x * w;
                acc[4 * q + 1] += c.y * w;
                acc[4 * q + 2] += c.z * w;
                acc[4 * q + 3] += c.w * w;
            }
        }
        const float bh = b_in[h];
        #pragma unroll
        for (int d = 0; d < DD; ++d) {
            hidT[h][d] = gelu_exact(acc[d] + bh);
        }
    }
    __syncthreads();

    // ---------- Phase 2: scores = gelu(hid @ w_a1 + b_a1) @ w_a2 ----------
    // wave wv handles d in [16*wv, 16*wv+16); lane j = attn-hidden index.
    {
        float a16[16];
        #pragma unroll
        for (int i = 0; i < 16; ++i) a16[i] = 0.0f;
        const int dbase = wv * 16;
        for (int hh = 0; hh < HH; ++hh) {
            const float w = w_a1[hh * H4 + lane];
            const float4* hp = (const float4*)&hidT[hh][dbase];
            #pragma unroll
            for (int q = 0; q < 4; ++q) {
                const float4 c = hp[q];
                a16[4 * q + 0] += c.x * w;
                a16[4 * q + 1] += c.y * w;
                a16[4 * q + 2] += c.z * w;
                a16[4 * q + 3] += c.w * w;
            }
        }
        const float ba  = b_a1[lane];
        const float wa2 = w_a2[lane];
        #pragma unroll
        for (int i = 0; i < 16; ++i) {
            float v = gelu_exact(a16[i] + ba) * wa2;
            #pragma unroll
            for (int off = 32; off; off >>= 1) v += __shfl_xor(v, off, 64);
            if (lane == i) score_s[dbase + i] = v;   // raw sum; +b_a2 & mask later
        }
    }
    __syncthreads();

    // ---------- Phase 3: mask + softmax over d (one wave) ----------
    if (tid < 64) {
        const int m = mask[base + tid];
        float s = score_s[tid] + b_a2[0];
        if (!m) s = -10000.0f;
        const unsigned long long bal = __ballot(m != 0);
        float mx = s;
        #pragma unroll
        for (int off = 32; off; off >>= 1) mx = fmaxf(mx, __shfl_xor(mx, off, 64));
        const float p = expf(s - mx);
        float sm = p;
        #pragma unroll
        for (int off = 32; off; off >>= 1) sm += __shfl_xor(sm, off, 64);
        attn_s[tid] = p / sm;
        if (tid == 0) anyv_s = (bal != 0ULL) ? 1 : 0;
    }
    __syncthreads();

    // ---------- Phase 4: r[h'] = sum_d attn[d]*gelu(hid @ w_v1 + b_v1) ----------
    {
        float vacc[DD];
        #pragma unroll
        for (int d = 0; d < DD; ++d) vacc[d] = 0.0f;
        for (int hh = 0; hh < HH; ++hh) {
            const float w = w_v1[hh * HH + tid];
            const float4* hp = (const float4*)&hidT[hh][0];
            #pragma unroll
            for (int q = 0; q < 16; ++q) {
                const float4 c = hp[q];
                vacc[4 * q + 0] += c.x * w;
                vacc[4 * q + 1] += c.y * w;
                vacc[4 * q + 2] += c.z * w;
                vacc[4 * q + 3] += c.w * w;
            }
        }
        const float bv = b_v1[tid];
        float r = 0.0f;
        #pragma unroll
        for (int d = 0; d < DD; ++d) {
            r += attn_s[d] * gelu_exact(vacc[d] + bv);
        }
        r_s[tid] = r;
    }
    __syncthreads();

    // ---------- Phase 5: out = r @ w_v2 + b_v2 (or fallback) ----------
    {
        float oacc = b_v2[tid];
        for (int hh = 0; hh < HH; hh += 4) {
            const float4 rv = *(const float4*)&r_s[hh];
            oacc += rv.x * w_v2[(hh + 0) * HH + tid];
            oacc += rv.y * w_v2[(hh + 1) * HH + tid];
            oacc += rv.z * w_v2[(hh + 2) * HH + tid];
            oacc += rv.w * w_v2[(hh + 3) * HH + tid];
        }
        if (!anyv_s) oacc = fb[tid];
        out[(long)blk * HH + tid] = oacc;
    }
}

extern "C" void kernel_launch(void* const* d_in, const int* in_sizes, int n_in,
                              void* d_out, int out_size, void* d_ws, size_t ws_size,
                              hipStream_t stream) {
    const int*   a1    = (const int*)  d_in[0];
    const int*   a2    = (const int*)  d_in[1];
    const float* dist  = (const float*)d_in[2];
    const int*   mask  = (const int*)  d_in[3];
    const float* table = (const float*)d_in[4];
    const float* w_in  = (const float*)d_in[5];
    const float* b_in  = (const float*)d_in[6];
    const float* w_a1  = (const float*)d_in[7];
    const float* b_a1  = (const float*)d_in[8];
    const float* w_a2  = (const float*)d_in[9];
    const float* b_a2  = (const float*)d_in[10];
    const float* w_v1  = (const float*)d_in[11];
    const float* b_v1  = (const float*)d_in[12];
    const float* w_v2  = (const float*)d_in[13];
    const float* b_v2  = (const float*)d_in[14];
    const float* fb    = (const float*)d_in[15];
    float* out = (float*)d_out;

    dist_attn_kernel<<<BW, 256, 0, stream>>>(a1, a2, dist, mask, table,
                                             w_in, b_in, w_a1, b_a1, w_a2, b_a2,
                                             w_v1, b_v1, w_v2, b_v2, fb, out);
}

// Round 3
// 153.061 us; speedup vs baseline: 8.6460x; 8.6460x over previous
//
#include <hip/hip_runtime.h>
#include <math.h>

#define BW 4096
#define DD 64
#define HH 256

typedef __bf16 bf16x8 __attribute__((ext_vector_type(8)));
typedef float  f32x4  __attribute__((ext_vector_type(4)));
typedef unsigned short u16x8 __attribute__((ext_vector_type(8)));

// ws layout (in ushorts): packed bf16 B-fragments for mfma_f32_16x16x32_bf16
// frag(kt,ct): lane l holds B[kt*32 + (l>>4)*8 + j][ct*16 + (l&15)], j=0..7
#define WIN_OFF 0        // w_in rows 0..63: KT=2,  NT=16 -> 2048 chunks
#define WA1_OFF 16384    // w_a1:           KT=8,  NT=4  -> 2048 chunks
#define WV1_OFF 32768    // w_v1:           KT=8,  NT=16 -> 8192 chunks
// total 12288 chunks * 8 shorts = 98304 shorts = 196608 bytes of ws

__device__ __forceinline__ unsigned short bf16_rne(float f) {
    union { float f; unsigned int u; } c; c.f = f;
    unsigned int u = c.u;
    return (unsigned short)((u + 0x7FFFu + ((u >> 16) & 1u)) >> 16);
}

// exact-erf GELU via Abramowitz-Stegun 7.1.26 (|err| <= 1.5e-7)
__device__ __forceinline__ float gelu_fast(float x) {
    float a = fabsf(x) * 0.70710678118654752f;
    float t = __builtin_amdgcn_rcpf(1.0f + 0.3275911f * a);
    float poly = ((((1.061405429f * t - 1.453152027f) * t + 1.421413741f) * t
                    - 0.284496736f) * t + 0.254829592f) * t;
    float erfa = 1.0f - poly * __expf(-a * a);
    return 0.5f * x * (1.0f + copysignf(erfa, x));
}

__device__ __forceinline__ f32x4 mfma16(bf16x8 a, bf16x8 b, f32x4 c) {
    return __builtin_amdgcn_mfma_f32_16x16x32_bf16(a, b, c, 0, 0, 0);
}

// ---------------- weight pre-pack: f32 -> bf16 MFMA B-fragments ----------------
__global__ void pack_weights(const float* __restrict__ w_in,
                             const float* __restrict__ w_a1,
                             const float* __restrict__ w_v1,
                             unsigned short* __restrict__ ws) {
    int t = blockIdx.x * 256 + threadIdx.x;   // chunk id, 12288 total
    if (t >= 12288) return;
    const float* src; int N, off, c;
    if (t < 2048)      { src = w_in; N = 256; off = WIN_OFF; c = t; }
    else if (t < 4096) { src = w_a1; N = 64;  off = WA1_OFF; c = t - 2048; }
    else               { src = w_v1; N = 256; off = WV1_OFF; c = t - 4096; }
    int lane = c & 63;
    int ctk  = c >> 6;                        // = kt*NT + ct
    int NT   = (N == 64) ? 4 : 16;
    int kt   = ctk / NT;
    int ct   = ctk - kt * NT;
    int k0   = kt * 32 + (lane >> 4) * 8;
    int n    = ct * 16 + (lane & 15);
    u16x8 v;
    #pragma unroll
    for (int j = 0; j < 8; ++j) v[j] = bf16_rne(src[(size_t)(k0 + j) * N + n]);
    *(u16x8*)(ws + off + (size_t)c * 8) = v;
}

// ---------------- main fused kernel: one block per (b,w) position ----------------
__global__ __launch_bounds__(256, 3)
void dist_attn_kernel(const int*   __restrict__ a1,
                      const int*   __restrict__ a2,
                      const float* __restrict__ dist,
                      const int*   __restrict__ mask,
                      const float* __restrict__ table,   // [101][32] f32
                      const float* __restrict__ w_in,    // [65][256] f32 (row 64 + bias path)
                      const float* __restrict__ b_in,
                      const float* __restrict__ b_a1,
                      const float* __restrict__ w_a2,
                      const float* __restrict__ b_a2,
                      const float* __restrict__ b_v1,
                      const float* __restrict__ w_v2,    // [256][256] f32
                      const float* __restrict__ b_v2,
                      const float* __restrict__ fb,
                      const unsigned short* __restrict__ ws,  // packed bf16 frags
                      float*       __restrict__ out) {
    // A-fragment-ordered LDS: frag[rt][ks][lane][j] = M[16*rt + (lane&15)][ks*32 + (lane>>4)*8 + j]
    __shared__ __align__(16) unsigned short combfrag[4][2][64][8];  // 8 KB  (e1|e2, K=64)
    __shared__ __align__(16) unsigned short hidfrag[4][8][64][8];   // 32 KB (hidden, K=256)
    __shared__ float dm_s[64];
    __shared__ int   mask_s[64];
    __shared__ float scorep[4][64];
    __shared__ float attn_s[64];
    __shared__ float r_s[256];
    __shared__ float outp[4][256];
    __shared__ int   anyv_s;

    const int tid = threadIdx.x;
    const int l   = tid & 63;
    const int w   = tid >> 6;       // wave id
    const int g   = l >> 4;         // k-group within wave
    const int li  = l & 15;
    const int blk = blockIdx.x;
    const long base = (long)blk * DD;

    // ---- P0: build comb A-frags (rows 16w..16w+15 handled by wave w) + dist/mask ----
    {
        const int i1 = a1[base + 16 * w + li];
        const int i2 = a2[base + 16 * w + li];
        #pragma unroll
        for (int ks = 0; ks < 2; ++ks) {
            const int idx = ks ? i2 : i1;
            const float* srcp = table + (size_t)idx * 32 + 8 * g;
            f32x4 v0 = *(const f32x4*)srcp;
            f32x4 v1 = *(const f32x4*)(srcp + 4);
            u16x8 u;
            #pragma unroll
            for (int j = 0; j < 4; ++j) { u[j] = bf16_rne(v0[j]); u[j + 4] = bf16_rne(v1[j]); }
            *(u16x8*)&combfrag[w][ks][l][0] = u;
        }
        if (tid < 64) {
            const int m = mask[base + tid];
            dm_s[tid]   = dist[base + tid] * (m ? 1.0f : 0.0f);
            mask_s[tid] = m;
            int any = __any(m != 0);
            if (tid == 0) anyv_s = any;
        }
    }
    __syncthreads();

    // ---- P1 (M1): hidden = gelu(comb@w_in[0:64] + dm*w_in[64] + b_in) -> hidfrag bf16 ----
    {
        bf16x8 ca[4][2];
        #pragma unroll
        for (int rt = 0; rt < 4; ++rt)
            #pragma unroll
            for (int ks = 0; ks < 2; ++ks)
                ca[rt][ks] = *(const bf16x8*)&combfrag[rt][ks][l][0];
        f32x4 dm4[4];
        #pragma unroll
        for (int rt = 0; rt < 4; ++rt) dm4[rt] = *(const f32x4*)&dm_s[16 * rt + 4 * g];

        #pragma unroll
        for (int ct = 0; ct < 4; ++ct) {
            const int ctg = 4 * w + ct;
            const int c   = 64 * w + 16 * ct + li;
            bf16x8 b0 = *(const bf16x8*)(ws + WIN_OFF + (size_t)((0 * 16 + ctg) * 64 + l) * 8);
            bf16x8 b1 = *(const bf16x8*)(ws + WIN_OFF + (size_t)((1 * 16 + ctg) * 64 + l) * 8);
            const float w64c = w_in[64 * 256 + c];
            const float binc = b_in[c];
            const int ks_c = c >> 5;
            const int jc   = c & 7;
            const int cg   = (c & 31) >> 3;
            unsigned short* dst = &hidfrag[0][ks_c][0][0];
            #pragma unroll
            for (int rt = 0; rt < 4; ++rt) {
                f32x4 acc = {0.f, 0.f, 0.f, 0.f};
                acc = mfma16(ca[rt][0], b0, acc);
                acc = mfma16(ca[rt][1], b1, acc);
                unsigned short* drt = dst + (size_t)rt * 8 * 64 * 8;
                #pragma unroll
                for (int p = 0; p < 4; ++p) {
                    float h = gelu_fast(acc[p] + dm4[rt][p] * w64c + binc);
                    int lanep = (4 * g + p) + 16 * cg;
                    drt[lanep * 8 + jc] = bf16_rne(h);
                }
            }
        }
    }
    __syncthreads();

    // ---- P2 (M2): scores partial = sum_col gelu(hid@w_a1 + b_a1)*w_a2 (wave w -> cols 16w..) ----
    {
        const float ba1 = b_a1[16 * w + li];
        const float wa2 = w_a2[16 * w + li];
        #pragma unroll
        for (int rt = 0; rt < 4; ++rt) {
            f32x4 acc = {0.f, 0.f, 0.f, 0.f};
            #pragma unroll
            for (int kt = 0; kt < 8; ++kt) {
                bf16x8 a = *(const bf16x8*)&hidfrag[rt][kt][l][0];
                bf16x8 b = *(const bf16x8*)(ws + WA1_OFF + (size_t)((kt * 4 + w) * 64 + l) * 8);
                acc = mfma16(a, b, acc);
            }
            float s[4];
            #pragma unroll
            for (int p = 0; p < 4; ++p) s[p] = gelu_fast(acc[p] + ba1) * wa2;
            #pragma unroll
            for (int off = 1; off <= 8; off <<= 1)
                #pragma unroll
                for (int p = 0; p < 4; ++p) s[p] += __shfl_xor(s[p], off, 64);
            if (li == 0) {
                f32x4 sv; sv[0] = s[0]; sv[1] = s[1]; sv[2] = s[2]; sv[3] = s[3];
                *(f32x4*)&scorep[w][16 * rt + 4 * g] = sv;
            }
        }
    }
    __syncthreads();

    // ---- P3: softmax over d (wave 0) ----
    if (tid < 64) {
        float sc = scorep[0][tid] + scorep[1][tid] + scorep[2][tid] + scorep[3][tid] + b_a2[0];
        if (!mask_s[tid]) sc = -10000.0f;
        float mx = sc;
        #pragma unroll
        for (int off = 32; off; off >>= 1) mx = fmaxf(mx, __shfl_xor(mx, off, 64));
        float p = __expf(sc - mx);
        float sm = p;
        #pragma unroll
        for (int off = 32; off; off >>= 1) sm += __shfl_xor(sm, off, 64);
        attn_s[tid] = p / sm;
    }
    __syncthreads();

    // ---- P4 (M3): r[c] = sum_d attn[d]*gelu(hid@w_v1 + b_v1)[d][c]  (wave w -> cols 64w..) ----
    {
        f32x4 acc3[4][4];   // [ct][rt]
        #pragma unroll
        for (int ct = 0; ct < 4; ++ct)
            #pragma unroll
            for (int rt = 0; rt < 4; ++rt) acc3[ct][rt] = (f32x4){0.f, 0.f, 0.f, 0.f};
        #pragma unroll
        for (int kt = 0; kt < 8; ++kt) {
            bf16x8 a[4];
            #pragma unroll
            for (int rt = 0; rt < 4; ++rt) a[rt] = *(const bf16x8*)&hidfrag[rt][kt][l][0];
            #pragma unroll
            for (int ct = 0; ct < 4; ++ct) {
                bf16x8 b = *(const bf16x8*)(ws + WV1_OFF + (size_t)((kt * 16 + 4 * w + ct) * 64 + l) * 8);
                #pragma unroll
                for (int rt = 0; rt < 4; ++rt) acc3[ct][rt] = mfma16(a[rt], b, acc3[ct][rt]);
            }
        }
        f32x4 av[4];
        #pragma unroll
        for (int rt = 0; rt < 4; ++rt) av[rt] = *(const f32x4*)&attn_s[16 * rt + 4 * g];
        #pragma unroll
        for (int ct = 0; ct < 4; ++ct) {
            const int c = 64 * w + 16 * ct + li;
            const float bv = b_v1[c];
            float val = 0.f;
            #pragma unroll
            for (int rt = 0; rt < 4; ++rt)
                #pragma unroll
                for (int p = 0; p < 4; ++p)
                    val += av[rt][p] * gelu_fast(acc3[ct][rt][p] + bv);
            val += __shfl_xor(val, 16, 64);
            val += __shfl_xor(val, 32, 64);
            if (g == 0) r_s[c] = val;
        }
    }
    __syncthreads();

    // ---- P5: out = r @ w_v2 + b_v2 (f32, split-K by wave), fallback select ----
    {
        f32x4 rv[16];
        #pragma unroll
        for (int q = 0; q < 16; ++q) rv[q] = *(const f32x4*)&r_s[64 * w + 4 * q];
        float part[4] = {0.f, 0.f, 0.f, 0.f};
        const float* wp = w_v2 + (size_t)(64 * w) * 256;
        #pragma unroll
        for (int q = 0; q < 16; ++q)
            #pragma unroll
            for (int e = 0; e < 4; ++e) {
                const float* row = wp + (size_t)(4 * q + e) * 256;
                #pragma unroll
                for (int ci = 0; ci < 4; ++ci) part[ci] += rv[q][e] * row[64 * ci + l];
            }
        #pragma unroll
        for (int ci = 0; ci < 4; ++ci) outp[w][64 * ci + l] = part[ci];
    }
    __syncthreads();
    {
        float o = outp[0][tid] + outp[1][tid] + outp[2][tid] + outp[3][tid] + b_v2[tid];
        if (!anyv_s) o = fb[tid];
        out[(size_t)blk * HH + tid] = o;
    }
}

extern "C" void kernel_launch(void* const* d_in, const int* in_sizes, int n_in,
                              void* d_out, int out_size, void* d_ws, size_t ws_size,
                              hipStream_t stream) {
    const int*   a1    = (const int*)  d_in[0];
    const int*   a2    = (const int*)  d_in[1];
    const float* dist  = (const float*)d_in[2];
    const int*   mask  = (const int*)  d_in[3];
    const float* table = (const float*)d_in[4];
    const float* w_in  = (const float*)d_in[5];
    const float* b_in  = (const float*)d_in[6];
    const float* w_a1  = (const float*)d_in[7];
    const float* b_a1  = (const float*)d_in[8];
    const float* w_a2  = (const float*)d_in[9];
    const float* b_a2  = (const float*)d_in[10];
    const float* w_v1  = (const float*)d_in[11];
    const float* b_v1  = (const float*)d_in[12];
    const float* w_v2  = (const float*)d_in[13];
    const float* b_v2  = (const float*)d_in[14];
    const float* fb    = (const float*)d_in[15];
    float* out = (float*)d_out;
    unsigned short* ws = (unsigned short*)d_ws;

    pack_weights<<<48, 256, 0, stream>>>(w_in, w_a1, w_v1, ws);
    dist_attn_kernel<<<BW, 256, 0, stream>>>(a1, a2, dist, mask, table,
                                             w_in, b_in, b_a1, w_a2, b_a2,
                                             b_v1, w_v2, b_v2, fb, ws, out);
}

// Round 4
// 141.211 us; speedup vs baseline: 9.3716x; 1.0839x over previous
//
#include <hip/hip_runtime.h>
#include <math.h>

#define BW 4096
#define DD 64
#define HH 256

typedef __bf16 bf16x8 __attribute__((ext_vector_type(8)));
typedef float  f32x4  __attribute__((ext_vector_type(4)));
typedef unsigned short u16x8 __attribute__((ext_vector_type(8)));

// ws layout (in ushorts), fragments for mfma_f32_16x16x32_bf16:
//
// WIN: A-frags of w_inT (standard k-bijection k=8g+j), frag(kin,ht), kin 0..1, ht 0..15:
//   chunk c = (kin*16+ht)*64 + lane; val j = w_in[kin*32 + 8*(lane>>4) + j][16*ht + (lane&15)]
// WA1: B-frags, HID k-bijection k_local = 16*(j>>2) + 4*(lane>>4) + (j&3), frag(kt,ct), kt 0..7, ct 0..3:
//   chunk c = (kt*4+ct)*64 + lane; val j = w_a1[kt*32 + bij][ct*16 + (lane&15)]
// WV1: B-frags, HID k-bijection, frag(kt,ct), kt 0..7, ct 0..15:
//   chunk c = (kt*16+ct)*64 + lane; val j = w_v1[kt*32 + bij][ct*16 + (lane&15)]
#define WIN_OFF 0
#define WA1_OFF 16384
#define WV1_OFF 32768
// total 12288 chunks * 8 ushorts = 196608 bytes of ws

__device__ __forceinline__ unsigned short to_bf16u(float f) {
    union { __bf16 b; unsigned short u; } cv;
    cv.b = (__bf16)f;           // RNE
    return cv.u;
}

// exact-erf GELU via Abramowitz-Stegun 7.1.26 (|err| <= 1.5e-7)
__device__ __forceinline__ float gelu_fast(float x) {
    float a = fabsf(x) * 0.70710678118654752f;
    float t = __builtin_amdgcn_rcpf(1.0f + 0.3275911f * a);
    float poly = ((((1.061405429f * t - 1.453152027f) * t + 1.421413741f) * t
                    - 0.284496736f) * t + 0.254829592f) * t;
    float erfa = 1.0f - poly * __expf(-a * a);
    return 0.5f * x * (1.0f + copysignf(erfa, x));
}

__device__ __forceinline__ f32x4 mfma16(bf16x8 a, bf16x8 b, f32x4 c) {
    return __builtin_amdgcn_mfma_f32_16x16x32_bf16(a, b, c, 0, 0, 0);
}

// ---------------- weight pre-pack ----------------
__global__ void pack_weights(const float* __restrict__ w_in,
                             const float* __restrict__ w_a1,
                             const float* __restrict__ w_v1,
                             unsigned short* __restrict__ ws) {
    int t = blockIdx.x * 256 + threadIdx.x;   // chunk id, 12288 total
    if (t >= 12288) return;
    int lane = t & 63;
    int g = lane >> 4, li = lane & 15;
    u16x8 v;
    if (t < 2048) {
        // WIN A-frag (transposed w_in), standard bijection
        int fr = t >> 6;              // 0..31
        int kin = fr >> 4, ht = fr & 15;
        #pragma unroll
        for (int j = 0; j < 8; ++j) {
            int k = kin * 32 + 8 * g + j;          // w_in row (input feature)
            v[j] = to_bf16u(w_in[(size_t)k * 256 + 16 * ht + li]);
        }
        *(u16x8*)(ws + WIN_OFF + (size_t)t * 8) = v;
    } else if (t < 4096) {
        int c = t - 2048;
        int fr = c >> 6;              // 0..31
        int kt = fr >> 2, ct = fr & 3;
        #pragma unroll
        for (int j = 0; j < 8; ++j) {
            int k = kt * 32 + 16 * (j >> 2) + 4 * g + (j & 3);   // HID bijection
            v[j] = to_bf16u(w_a1[(size_t)k * 64 + ct * 16 + li]);
        }
        *(u16x8*)(ws + WA1_OFF + (size_t)c * 8) = v;
    } else {
        int c = t - 4096;
        int fr = c >> 6;              // 0..127
        int kt = fr >> 4, ct = fr & 15;
        #pragma unroll
        for (int j = 0; j < 8; ++j) {
            int k = kt * 32 + 16 * (j >> 2) + 4 * g + (j & 3);   // HID bijection
            v[j] = to_bf16u(w_v1[(size_t)k * 256 + ct * 16 + li]);
        }
        *(u16x8*)(ws + WV1_OFF + (size_t)c * 8) = v;
    }
}

// ---------------- main fused kernel: one block per (b,w) position ----------------
__global__ __launch_bounds__(256, 4)
void dist_attn_kernel(const int*   __restrict__ a1,
                      const int*   __restrict__ a2,
                      const float* __restrict__ dist,
                      const int*   __restrict__ mask,
                      const float* __restrict__ table,   // [101][32] f32
                      const float* __restrict__ w_in,    // [65][256] f32 (row 64 used)
                      const float* __restrict__ b_in,
                      const float* __restrict__ b_a1,
                      const float* __restrict__ w_a2,
                      const float* __restrict__ b_a2,
                      const float* __restrict__ b_v1,
                      const float* __restrict__ w_v2,    // [256][256] f32
                      const float* __restrict__ b_v2,
                      const float* __restrict__ fb,
                      const unsigned short* __restrict__ ws,
                      float*       __restrict__ out) {
    // sU union: P0-P1: comb B-frags (8192B). P2+: scorep/attn/r_s/anyv/outp.
    __shared__ __align__(16) unsigned char sU[8192];
    // hidfrag[dt][kt][lane][j] = hid[d=16dt+(lane&15)][h=kt*32 + 16*(j>>2)+4*(lane>>4)+(j&3)]
    __shared__ __align__(16) unsigned short hidfrag[4][8][64][8];  // 32768B; total 40960B

    unsigned short (*combfrag)[2][64][8] = (unsigned short (*)[2][64][8])sU;
    float* scorep = (float*)sU;              // [4][64]  @0     (P2->P3)
    float* attn_s = (float*)(sU + 1024);     // [64]     @1024  (P3->P4)
    float* r_s    = (float*)(sU + 1280);     // [256]    @1280  (P4->P5)
    int*   anyv_s = (int*)  (sU + 2304);     //          @2304  (P3->P6)
    float* outp   = (float*)(sU + 2320);     // [4][256] @2320  (P5->P6)

    const int tid = threadIdx.x;
    const int l   = tid & 63;
    const int w   = tid >> 6;
    const int g   = l >> 4;
    const int li  = l & 15;
    const int blk = blockIdx.x;
    const long base = (long)blk * DD;

    // ---- P0: wave w builds comb B-frag tile dt=w (pairs d = 16w+li) ----
    {
        const int i1 = a1[base + 16 * w + li];
        const int i2 = a2[base + 16 * w + li];
        #pragma unroll
        for (int ks = 0; ks < 2; ++ks) {
            const int idx = ks ? i2 : i1;
            const float* srcp = table + (size_t)idx * 32 + 8 * g;
            f32x4 v0 = *(const f32x4*)srcp;
            f32x4 v1 = *(const f32x4*)(srcp + 4);
            u16x8 u;
            #pragma unroll
            for (int j = 0; j < 4; ++j) { u[j] = to_bf16u(v0[j]); u[j + 4] = to_bf16u(v1[j]); }
            *(u16x8*)&combfrag[w][ks][l][0] = u;
        }
    }
    __syncthreads();

    // ---- P1': hidT = w_inT @ combT + dm*w64 + b_in, gelu -> hidfrag (register-native A-frags) ----
    {
        bf16x8 cb[4][2];
        #pragma unroll
        for (int dt = 0; dt < 4; ++dt)
            #pragma unroll
            for (int ks = 0; ks < 2; ++ks)
                cb[dt][ks] = *(const bf16x8*)&combfrag[dt][ks][l][0];
        float dmv[4];
        #pragma unroll
        for (int dt = 0; dt < 4; ++dt) {
            int m = mask[base + 16 * dt + li];
            dmv[dt] = m ? dist[base + 16 * dt + li] : 0.0f;
        }
        #pragma unroll
        for (int hp = 0; hp < 2; ++hp) {          // own k-tile: kt = 2w+hp
            u16x8 pend[4];
            #pragma unroll
            for (int b = 0; b < 2; ++b) {
                const int ht = 4 * w + 2 * hp + b;
                bf16x8 af0 = *(const bf16x8*)(ws + WIN_OFF + ((0 * 16 + ht) * 64 + l) * 8);
                bf16x8 af1 = *(const bf16x8*)(ws + WIN_OFF + ((1 * 16 + ht) * 64 + l) * 8);
                f32x4 w64v = *(const f32x4*)&w_in[64 * 256 + 16 * ht + 4 * g];
                f32x4 binv = *(const f32x4*)&b_in[16 * ht + 4 * g];
                #pragma unroll
                for (int dt = 0; dt < 4; ++dt) {
                    f32x4 acc = {0.f, 0.f, 0.f, 0.f};
                    acc = mfma16(af0, cb[dt][0], acc);
                    acc = mfma16(af1, cb[dt][1], acc);
                    #pragma unroll
                    for (int p = 0; p < 4; ++p) {
                        float h = gelu_fast(acc[p] + dmv[dt] * w64v[p] + binv[p]);
                        pend[dt][4 * b + p] = to_bf16u(h);
                    }
                }
            }
            #pragma unroll
            for (int dt = 0; dt < 4; ++dt)
                *(u16x8*)&hidfrag[dt][2 * w + hp][l][0] = pend[dt];
        }
    }
    __syncthreads();

    // ---- P2: score partials = sum_col gelu(hid@w_a1 + b_a1)*w_a2 (wave w -> cols 16w..) ----
    {
        const float ba1 = b_a1[16 * w + li];
        const float wa2 = w_a2[16 * w + li];
        #pragma unroll
        for (int rt = 0; rt < 4; ++rt) {
            f32x4 acc = {0.f, 0.f, 0.f, 0.f};
            #pragma unroll
            for (int kt = 0; kt < 8; ++kt) {
                bf16x8 a = *(const bf16x8*)&hidfrag[rt][kt][l][0];
                bf16x8 b = *(const bf16x8*)(ws + WA1_OFF + ((kt * 4 + w) * 64 + l) * 8);
                acc = mfma16(a, b, acc);
            }
            float s[4];
            #pragma unroll
            for (int p = 0; p < 4; ++p) s[p] = gelu_fast(acc[p] + ba1) * wa2;
            #pragma unroll
            for (int off = 1; off <= 8; off <<= 1)
                #pragma unroll
                for (int p = 0; p < 4; ++p) s[p] += __shfl_xor(s[p], off, 64);
            if (li == 0) {
                f32x4 sv; sv[0] = s[0]; sv[1] = s[1]; sv[2] = s[2]; sv[3] = s[3];
                *(f32x4*)&scorep[w * 64 + 16 * rt + 4 * g] = sv;
            }
        }
    }
    __syncthreads();

    // ---- P3: softmax over d (wave 0) ----
    if (tid < 64) {
        const int m = mask[base + tid];
        int any = __any(m != 0);
        float sc = scorep[tid] + scorep[64 + tid] + scorep[128 + tid] + scorep[192 + tid] + b_a2[0];
        if (!m) sc = -10000.0f;
        float mx = sc;
        #pragma unroll
        for (int off = 32; off; off >>= 1) mx = fmaxf(mx, __shfl_xor(mx, off, 64));
        float p = __expf(sc - mx);
        float sm = p;
        #pragma unroll
        for (int off = 32; off; off >>= 1) sm += __shfl_xor(sm, off, 64);
        attn_s[tid] = p / sm;
        if (tid == 0) *anyv_s = any;
    }
    __syncthreads();

    // ---- P4: r[c] = sum_d attn[d]*gelu(hid@w_v1 + b_v1)[d][c]  (wave w -> cols 64w..) ----
    {
        f32x4 acc3[4][4];   // [ct][rt]
        #pragma unroll
        for (int ct = 0; ct < 4; ++ct)
            #pragma unroll
            for (int rt = 0; rt < 4; ++rt) acc3[ct][rt] = (f32x4){0.f, 0.f, 0.f, 0.f};
        #pragma unroll
        for (int kt = 0; kt < 8; ++kt) {
            bf16x8 a[4];
            #pragma unroll
            for (int rt = 0; rt < 4; ++rt) a[rt] = *(const bf16x8*)&hidfrag[rt][kt][l][0];
            #pragma unroll
            for (int ct = 0; ct < 4; ++ct) {
                bf16x8 b = *(const bf16x8*)(ws + WV1_OFF + ((kt * 16 + 4 * w + ct) * 64 + l) * 8);
                #pragma unroll
                for (int rt = 0; rt < 4; ++rt) acc3[ct][rt] = mfma16(a[rt], b, acc3[ct][rt]);
            }
        }
        f32x4 av[4];
        #pragma unroll
        for (int rt = 0; rt < 4; ++rt) av[rt] = *(const f32x4*)&attn_s[16 * rt + 4 * g];
        #pragma unroll
        for (int ct = 0; ct < 4; ++ct) {
            const int c = 64 * w + 16 * ct + li;
            const float bv = b_v1[c];
            float val = 0.f;
            #pragma unroll
            for (int rt = 0; rt < 4; ++rt)
                #pragma unroll
                for (int p = 0; p < 4; ++p)
                    val += av[rt][p] * gelu_fast(acc3[ct][rt][p] + bv);
            val += __shfl_xor(val, 16, 64);
            val += __shfl_xor(val, 32, 64);
            if (g == 0) r_s[c] = val;
        }
    }
    __syncthreads();

    // ---- P5: out = r @ w_v2 (f32, split-K by wave, float4 loads) ----
    {
        const float* wp = w_v2 + (size_t)(64 * w) * 256 + 4 * l;
        f32x4 part = {0.f, 0.f, 0.f, 0.f};
        #pragma unroll 4
        for (int q = 0; q < 64; q += 4) {
            f32x4 rv = *(const f32x4*)&r_s[64 * w + q];
            #pragma unroll
            for (int e = 0; e < 4; ++e) {
                f32x4 wv = *(const f32x4*)(wp + (size_t)(q + e) * 256);
                part[0] += rv[e] * wv[0];
                part[1] += rv[e] * wv[1];
                part[2] += rv[e] * wv[2];
                part[3] += rv[e] * wv[3];
            }
        }
        *(f32x4*)&outp[w * 256 + 4 * l] = part;
    }
    __syncthreads();

    // ---- P6: reduce partials + bias, fallback select, store ----
    {
        float o = outp[tid] + outp[256 + tid] + outp[512 + tid] + outp[768 + tid] + b_v2[tid];
        if (!*anyv_s) o = fb[tid];
        out[(size_t)blk * HH + tid] = o;
    }
}

extern "C" void kernel_launch(void* const* d_in, const int* in_sizes, int n_in,
                              void* d_out, int out_size, void* d_ws, size_t ws_size,
                              hipStream_t stream) {
    const int*   a1    = (const int*)  d_in[0];
    const int*   a2    = (const int*)  d_in[1];
    const float* dist  = (const float*)d_in[2];
    const int*   mask  = (const int*)  d_in[3];
    const float* table = (const float*)d_in[4];
    const float* w_in  = (const float*)d_in[5];
    const float* b_in  = (const float*)d_in[6];
    const float* w_a1  = (const float*)d_in[7];
    const float* b_a1  = (const float*)d_in[8];
    const float* w_a2  = (const float*)d_in[9];
    const float* b_a2  = (const float*)d_in[10];
    const float* b_v1  = (const float*)d_in[12];
    const float* w_v2  = (const float*)d_in[13];
    const float* b_v2  = (const float*)d_in[14];
    const float* fb    = (const float*)d_in[15];
    const float* w_a1w = (const float*)d_in[7];
    const float* w_v1  = (const float*)d_in[11];
    float* out = (float*)d_out;
    unsigned short* ws = (unsigned short*)d_ws;

    pack_weights<<<48, 256, 0, stream>>>(w_in, w_a1w, w_v1, ws);
    dist_attn_kernel<<<BW, 256, 0, stream>>>(a1, a2, dist, mask, table,
                                             w_in, b_in, b_a1, w_a2, b_a2,
                                             b_v1, w_v2, b_v2, fb, ws, out);
    (void)w_a1;
}

// Round 5
// 128.080 us; speedup vs baseline: 10.3323x; 1.1025x over previous
//
#include <hip/hip_runtime.h>
#include <math.h>

#define BW 4096
#define DD 64
#define HH 256

typedef __bf16 bf16x8 __attribute__((ext_vector_type(8)));
typedef float  f32x4  __attribute__((ext_vector_type(4)));
typedef unsigned short u16x8 __attribute__((ext_vector_type(8)));

// ws layout (ushort units), fragments for mfma_f32_16x16x32_bf16:
// WIN: A-frags of w_inT, standard k-bij (k=8g+j).  frag(kin,ht): kin 0..1, ht 0..15
// WA1: B-frags, HID k-bij  k=16*(j>>2)+4g+(j&3).  frag(kt,ct):  kt 0..7,  ct 0..3
// WV1: B-frags, HID k-bij.                         frag(kt,ct):  kt 0..7,  ct 0..15
// WV2: B-frags, standard k-bij (k=8g+j).           frag(kt,ct):  kt 0..7,  ct 0..15
#define WIN_OFF 0
#define WA1_OFF 16384
#define WV1_OFF 32768
#define WV2_OFF 98304
// total (2048+2048+8192+8192) chunks * 16B = 327680 bytes of ws

__device__ __forceinline__ unsigned short to_bf16u(float f) {
    union { __bf16 b; unsigned short u; } cv;
    cv.b = (__bf16)f;           // RNE
    return cv.u;
}

// tanh-form GELU via sigmoid: x * sigmoid(1.59577x + 0.0713548x^3)
// = x * rcp(1 + exp2(x*(-2.3022082 - 0.10294344 x^2)))
// |err vs exact-erf gelu| <= ~5e-4 abs; 5 VALU + 2 transcendental.
__device__ __forceinline__ float gelu_fast(float x) {
    float x2 = x * x;
    float z  = x * __builtin_fmaf(-0.10294344f, x2, -2.3022082f);
    float e  = __builtin_amdgcn_exp2f(z);
    return x * __builtin_amdgcn_rcpf(1.0f + e);
}

__device__ __forceinline__ f32x4 mfma16(bf16x8 a, bf16x8 b, f32x4 c) {
    return __builtin_amdgcn_mfma_f32_16x16x32_bf16(a, b, c, 0, 0, 0);
}

// ---------------- weight pre-pack ----------------
__global__ void pack_weights(const float* __restrict__ w_in,
                             const float* __restrict__ w_a1,
                             const float* __restrict__ w_v1,
                             const float* __restrict__ w_v2,
                             unsigned short* __restrict__ ws) {
    int t = blockIdx.x * 256 + threadIdx.x;   // chunk id, 20480 total
    if (t >= 20480) return;
    int lane = t & 63;
    int g = lane >> 4, li = lane & 15;
    u16x8 v;
    if (t < 2048) {
        int fr = t >> 6;                      // 0..31
        int kin = fr >> 4, ht = fr & 15;
        #pragma unroll
        for (int j = 0; j < 8; ++j) {
            int k = kin * 32 + 8 * g + j;
            v[j] = to_bf16u(w_in[(size_t)k * 256 + 16 * ht + li]);
        }
        *(u16x8*)(ws + WIN_OFF + (size_t)t * 8) = v;
    } else if (t < 4096) {
        int c = t - 2048;
        int fr = c >> 6;                      // 0..31
        int kt = fr >> 2, ct = fr & 3;
        #pragma unroll
        for (int j = 0; j < 8; ++j) {
            int k = kt * 32 + 16 * (j >> 2) + 4 * g + (j & 3);
            v[j] = to_bf16u(w_a1[(size_t)k * 64 + ct * 16 + li]);
        }
        *(u16x8*)(ws + WA1_OFF + (size_t)c * 8) = v;
    } else if (t < 12288) {
        int c = t - 4096;
        int fr = c >> 6;                      // 0..127
        int kt = fr >> 4, ct = fr & 15;
        #pragma unroll
        for (int j = 0; j < 8; ++j) {
            int k = kt * 32 + 16 * (j >> 2) + 4 * g + (j & 3);
            v[j] = to_bf16u(w_v1[(size_t)k * 256 + ct * 16 + li]);
        }
        *(u16x8*)(ws + WV1_OFF + (size_t)c * 8) = v;
    } else {
        int c = t - 12288;
        int fr = c >> 6;                      // 0..127
        int kt = fr >> 4, ct = fr & 15;
        #pragma unroll
        for (int j = 0; j < 8; ++j) {
            int k = kt * 32 + 8 * g + j;      // standard bijection (matches r A-frag)
            v[j] = to_bf16u(w_v2[(size_t)k * 256 + ct * 16 + li]);
        }
        *(u16x8*)(ws + WV2_OFF + (size_t)c * 8) = v;
    }
}

// ---------------- main fused kernel: one block per (b,w) position ----------------
__global__ __launch_bounds__(256, 4)
void dist_attn_kernel(const int*   __restrict__ a1,
                      const int*   __restrict__ a2,
                      const float* __restrict__ dist,
                      const int*   __restrict__ mask,
                      const float* __restrict__ table,   // [101][32] f32
                      const float* __restrict__ w_in,    // [65][256] f32 (row 64 used)
                      const float* __restrict__ b_in,
                      const float* __restrict__ b_a1,
                      const float* __restrict__ w_a2,
                      const float* __restrict__ b_a2,
                      const float* __restrict__ b_v1,
                      const float* __restrict__ b_v2,
                      const float* __restrict__ fb,
                      const unsigned short* __restrict__ ws,
                      float*       __restrict__ out) {
    // sU: P0-P1: comb B-frags (8192B). P2+: scorep @0 (1KB) | attn @1024 ([4][64] f32) | r_bf @2048 (512B)
    __shared__ __align__(16) unsigned char sU[8192];
    // hidfrag[dt][kt][lane][j] = hid[d=16dt+(lane&15)][h=kt*32 + 16*(j>>2)+4*(lane>>4)+(j&3)]
    __shared__ __align__(16) unsigned short hidfrag[4][8][64][8];  // 32768B; total 40960B

    unsigned short (*combfrag)[2][64][8] = (unsigned short (*)[2][64][8])sU;
    float*          scorep = (float*)sU;               // [4][64]
    float*          attn_s = (float*)(sU + 1024);      // [4][64] per-wave copies
    unsigned short* r_bf   = (unsigned short*)(sU + 2048);  // [256] bf16

    const int tid = threadIdx.x;
    const int l   = tid & 63;
    const int w   = tid >> 6;
    const int g   = l >> 4;
    const int li  = l & 15;
    const int blk = blockIdx.x;
    const long base = (long)blk * DD;

    // ---- P0: wave w builds comb B-frag tile dt=w (pairs d = 16w+li) ----
    {
        const int i1 = a1[base + 16 * w + li];
        const int i2 = a2[base + 16 * w + li];
        #pragma unroll
        for (int ks = 0; ks < 2; ++ks) {
            const int idx = ks ? i2 : i1;
            const float* srcp = table + (size_t)idx * 32 + 8 * g;
            f32x4 v0 = *(const f32x4*)srcp;
            f32x4 v1 = *(const f32x4*)(srcp + 4);
            u16x8 u;
            #pragma unroll
            for (int j = 0; j < 4; ++j) { u[j] = to_bf16u(v0[j]); u[j + 4] = to_bf16u(v1[j]); }
            *(u16x8*)&combfrag[w][ks][l][0] = u;
        }
    }
    __syncthreads();

    // ---- P1: hidT = w_inT @ combT (+ dm*w64 + b_in), gelu -> hidfrag (register-native A-frags) ----
    {
        bf16x8 cb[4][2];
        #pragma unroll
        for (int dt = 0; dt < 4; ++dt)
            #pragma unroll
            for (int ks = 0; ks < 2; ++ks)
                cb[dt][ks] = *(const bf16x8*)&combfrag[dt][ks][l][0];
        float dmv[4];
        #pragma unroll
        for (int dt = 0; dt < 4; ++dt) {
            int m = mask[base + 16 * dt + li];
            dmv[dt] = m ? dist[base + 16 * dt + li] : 0.0f;
        }
        #pragma unroll
        for (int hp = 0; hp < 2; ++hp) {          // own k-tile: kt = 2w+hp
            u16x8 pend[4];
            #pragma unroll
            for (int b = 0; b < 2; ++b) {
                const int ht = 4 * w + 2 * hp + b;
                bf16x8 af0 = *(const bf16x8*)(ws + WIN_OFF + ((0 * 16 + ht) * 64 + l) * 8);
                bf16x8 af1 = *(const bf16x8*)(ws + WIN_OFF + ((1 * 16 + ht) * 64 + l) * 8);
                f32x4 w64v = *(const f32x4*)&w_in[64 * 256 + 16 * ht + 4 * g];
                f32x4 binv = *(const f32x4*)&b_in[16 * ht + 4 * g];
                #pragma unroll
                for (int dt = 0; dt < 4; ++dt) {
                    f32x4 acc = {0.f, 0.f, 0.f, 0.f};
                    acc = mfma16(af0, cb[dt][0], acc);
                    acc = mfma16(af1, cb[dt][1], acc);
                    #pragma unroll
                    for (int p = 0; p < 4; ++p) {
                        float h = gelu_fast(acc[p] + dmv[dt] * w64v[p] + binv[p]);
                        pend[dt][4 * b + p] = to_bf16u(h);
                    }
                }
            }
            #pragma unroll
            for (int dt = 0; dt < 4; ++dt)
                *(u16x8*)&hidfrag[dt][2 * w + hp][l][0] = pend[dt];
        }
    }
    __syncthreads();

    // ---- P2: score partials (wave w -> attn-hidden cols 16w..16w+15) ----
    {
        const float ba1 = b_a1[16 * w + li];
        const float wa2 = w_a2[16 * w + li];
        f32x4 acc[4];
        #pragma unroll
        for (int rt = 0; rt < 4; ++rt) acc[rt] = (f32x4){0.f, 0.f, 0.f, 0.f};
        #pragma unroll
        for (int kt = 0; kt < 8; ++kt) {
            bf16x8 b = *(const bf16x8*)(ws + WA1_OFF + ((kt * 4 + w) * 64 + l) * 8);
            #pragma unroll
            for (int rt = 0; rt < 4; ++rt) {
                bf16x8 a = *(const bf16x8*)&hidfrag[rt][kt][l][0];
                acc[rt] = mfma16(a, b, acc[rt]);
            }
        }
        #pragma unroll
        for (int rt = 0; rt < 4; ++rt) {
            float s[4];
            #pragma unroll
            for (int p = 0; p < 4; ++p) s[p] = gelu_fast(acc[rt][p] + ba1) * wa2;
            #pragma unroll
            for (int off = 1; off <= 8; off <<= 1)
                #pragma unroll
                for (int p = 0; p < 4; ++p) s[p] += __shfl_xor(s[p], off, 64);
            if (li == 0) {
                f32x4 sv; sv[0] = s[0]; sv[1] = s[1]; sv[2] = s[2]; sv[3] = s[3];
                *(f32x4*)&scorep[w * 64 + 16 * rt + 4 * g] = sv;
            }
        }
    }
    __syncthreads();

    // ---- P3: softmax, redundant per wave (no extra barrier); anyv in register ----
    int anyv;
    {
        const int m = mask[base + l];
        anyv = __any(m != 0);
        float sc = scorep[l] + scorep[64 + l] + scorep[128 + l] + scorep[192 + l] + b_a2[0];
        if (!m) sc = -10000.0f;
        float mx = sc;
        #pragma unroll
        for (int off = 32; off; off >>= 1) mx = fmaxf(mx, __shfl_xor(mx, off, 64));
        float p = __expf(sc - mx);
        float sm = p;
        #pragma unroll
        for (int off = 32; off; off >>= 1) sm += __shfl_xor(sm, off, 64);
        attn_s[w * 64 + l] = p / sm;
    }
    // same-wave LDS RAW -> ordered by lgkmcnt, no __syncthreads needed

    // ---- P4: r[c] = sum_d attn[d]*gelu(hid@w_v1 + b_v1)[d][c]  (wave w -> cols 64w..) ----
    {
        f32x4 acc3[4][4];   // [ct][rt]
        #pragma unroll
        for (int ct = 0; ct < 4; ++ct)
            #pragma unroll
            for (int rt = 0; rt < 4; ++rt) acc3[ct][rt] = (f32x4){0.f, 0.f, 0.f, 0.f};
        #pragma unroll
        for (int kt = 0; kt < 8; ++kt) {
            bf16x8 a[4];
            #pragma unroll
            for (int rt = 0; rt < 4; ++rt) a[rt] = *(const bf16x8*)&hidfrag[rt][kt][l][0];
            #pragma unroll
            for (int ct = 0; ct < 4; ++ct) {
                bf16x8 b = *(const bf16x8*)(ws + WV1_OFF + ((kt * 16 + 4 * w + ct) * 64 + l) * 8);
                #pragma unroll
                for (int rt = 0; rt < 4; ++rt) acc3[ct][rt] = mfma16(a[rt], b, acc3[ct][rt]);
            }
        }
        f32x4 av[4];
        #pragma unroll
        for (int rt = 0; rt < 4; ++rt) av[rt] = *(const f32x4*)&attn_s[w * 64 + 16 * rt + 4 * g];
        #pragma unroll
        for (int ct = 0; ct < 4; ++ct) {
            const int c = 64 * w + 16 * ct + li;
            const float bv = b_v1[c];
            float val = 0.f;
            #pragma unroll
            for (int rt = 0; rt < 4; ++rt)
                #pragma unroll
                for (int p = 0; p < 4; ++p)
                    val += av[rt][p] * gelu_fast(acc3[ct][rt][p] + bv);
            val += __shfl_xor(val, 16, 64);
            val += __shfl_xor(val, 32, 64);
            if (g == 0) r_bf[c] = to_bf16u(val);
        }
    }
    __syncthreads();

    // ---- P5: out = r @ w_v2 via MFMA (r broadcast to all 16 A-rows), full K per wave ----
    {
        f32x4 acc[4];
        #pragma unroll
        for (int ct = 0; ct < 4; ++ct) acc[ct] = (f32x4){0.f, 0.f, 0.f, 0.f};
        #pragma unroll
        for (int kt = 0; kt < 8; ++kt) {
            bf16x8 a = *(const bf16x8*)&r_bf[kt * 32 + 8 * g];   // same for all li -> broadcast
            #pragma unroll
            for (int ct = 0; ct < 4; ++ct) {
                bf16x8 b = *(const bf16x8*)(ws + WV2_OFF + ((kt * 16 + 4 * w + ct) * 64 + l) * 8);
                acc[ct] = mfma16(a, b, acc[ct]);
            }
        }
        if (g == 0) {
            #pragma unroll
            for (int ct = 0; ct < 4; ++ct) {
                const int c = 16 * (4 * w + ct) + li;
                float o = acc[ct][0] + b_v2[c];
                if (!anyv) o = fb[c];
                out[(size_t)blk * HH + c] = o;
            }
        }
    }
}

extern "C" void kernel_launch(void* const* d_in, const int* in_sizes, int n_in,
                              void* d_out, int out_size, void* d_ws, size_t ws_size,
                              hipStream_t stream) {
    const int*   a1    = (const int*)  d_in[0];
    const int*   a2    = (const int*)  d_in[1];
    const float* dist  = (const float*)d_in[2];
    const int*   mask  = (const int*)  d_in[3];
    const float* table = (const float*)d_in[4];
    const float* w_in  = (const float*)d_in[5];
    const float* b_in  = (const float*)d_in[6];
    const float* w_a1  = (const float*)d_in[7];
    const float* b_a1  = (const float*)d_in[8];
    const float* w_a2  = (const float*)d_in[9];
    const float* b_a2  = (const float*)d_in[10];
    const float* w_v1  = (const float*)d_in[11];
    const float* b_v1  = (const float*)d_in[12];
    const float* w_v2  = (const float*)d_in[13];
    const float* b_v2  = (const float*)d_in[14];
    const float* fb    = (const float*)d_in[15];
    float* out = (float*)d_out;
    unsigned short* ws = (unsigned short*)d_ws;

    pack_weights<<<80, 256, 0, stream>>>(w_in, w_a1, w_v1, w_v2, ws);
    dist_attn_kernel<<<BW, 256, 0, stream>>>(a1, a2, dist, mask, table,
                                             w_in, b_in, b_a1, w_a2, b_a2,
                                             b_v1, b_v2, fb, ws, out);
}

// Round 6
// 102.315 us; speedup vs baseline: 12.9342x; 1.2518x over previous
//
#include <hip/hip_runtime.h>
#include <math.h>

#define BW 4096
#define DD 64
#define HH 256

typedef __bf16 bf16x8 __attribute__((ext_vector_type(8)));
typedef float  f32x4  __attribute__((ext_vector_type(4)));
typedef unsigned short u16x8 __attribute__((ext_vector_type(8)));

// ws layout (ushort units), fragments for mfma_f32_16x16x32_bf16:
// WIN: A-frags of w_inT, standard k-bij (k=8g+j).  frag(kin,ht): kin 0..1, ht 0..15
// WA1: B-frags, HID k-bij  k=16*(j>>2)+4g+(j&3).  frag(kt,ct):  kt 0..7,  ct 0..3
// WV1: B-frags, HID k-bij.                         frag(kt,ct):  kt 0..7,  ct 0..15
// WV2: B-frags, standard k-bij (k=8g+j).           frag(kt,ct):  kt 0..7,  ct 0..15
#define WIN_OFF 0
#define WA1_OFF 16384
#define WV1_OFF 32768
#define WV2_OFF 98304
// total (2048+2048+8192+8192) chunks * 16B = 327680 bytes of ws

__device__ __forceinline__ unsigned short to_bf16u(float f) {
    union { __bf16 b; unsigned short u; } cv;
    cv.b = (__bf16)f;           // RNE
    return cv.u;
}

// tanh-form GELU via sigmoid: x * sigmoid(1.59577x + 0.0713548x^3)
// = x * rcp(1 + exp2(x*(-2.3022082 - 0.10294344 x^2)))
// |err vs exact-erf gelu| <= ~5e-4 abs; 5 VALU + 2 transcendental.
__device__ __forceinline__ float gelu_fast(float x) {
    float x2 = x * x;
    float z  = x * __builtin_fmaf(-0.10294344f, x2, -2.3022082f);
    float e  = __builtin_amdgcn_exp2f(z);
    return x * __builtin_amdgcn_rcpf(1.0f + e);
}

__device__ __forceinline__ f32x4 mfma16(bf16x8 a, bf16x8 b, f32x4 c) {
    return __builtin_amdgcn_mfma_f32_16x16x32_bf16(a, b, c, 0, 0, 0);
}

// ---------------- weight pre-pack ----------------
__global__ void pack_weights(const float* __restrict__ w_in,
                             const float* __restrict__ w_a1,
                             const float* __restrict__ w_v1,
                             const float* __restrict__ w_v2,
                             unsigned short* __restrict__ ws) {
    int t = blockIdx.x * 256 + threadIdx.x;   // chunk id, 20480 total
    if (t >= 20480) return;
    int lane = t & 63;
    int g = lane >> 4, li = lane & 15;
    u16x8 v;
    if (t < 2048) {
        int fr = t >> 6;                      // 0..31
        int kin = fr >> 4, ht = fr & 15;
        #pragma unroll
        for (int j = 0; j < 8; ++j) {
            int k = kin * 32 + 8 * g + j;
            v[j] = to_bf16u(w_in[(size_t)k * 256 + 16 * ht + li]);
        }
        *(u16x8*)(ws + WIN_OFF + (size_t)t * 8) = v;
    } else if (t < 4096) {
        int c = t - 2048;
        int fr = c >> 6;                      // 0..31
        int kt = fr >> 2, ct = fr & 3;
        #pragma unroll
        for (int j = 0; j < 8; ++j) {
            int k = kt * 32 + 16 * (j >> 2) + 4 * g + (j & 3);
            v[j] = to_bf16u(w_a1[(size_t)k * 64 + ct * 16 + li]);
        }
        *(u16x8*)(ws + WA1_OFF + (size_t)c * 8) = v;
    } else if (t < 12288) {
        int c = t - 4096;
        int fr = c >> 6;                      // 0..127
        int kt = fr >> 4, ct = fr & 15;
        #pragma unroll
        for (int j = 0; j < 8; ++j) {
            int k = kt * 32 + 16 * (j >> 2) + 4 * g + (j & 3);
            v[j] = to_bf16u(w_v1[(size_t)k * 256 + ct * 16 + li]);
        }
        *(u16x8*)(ws + WV1_OFF + (size_t)c * 8) = v;
    } else {
        int c = t - 12288;
        int fr = c >> 6;                      // 0..127
        int kt = fr >> 4, ct = fr & 15;
        #pragma unroll
        for (int j = 0; j < 8; ++j) {
            int k = kt * 32 + 8 * g + j;      // standard bijection (matches r A-frag)
            v[j] = to_bf16u(w_v2[(size_t)k * 256 + ct * 16 + li]);
        }
        *(u16x8*)(ws + WV2_OFF + (size_t)c * 8) = v;
    }
}

// ---------------- main fused kernel: one block per (b,w) position ----------------
__global__ __launch_bounds__(256, 4)
void dist_attn_kernel(const int*   __restrict__ a1,
                      const int*   __restrict__ a2,
                      const float* __restrict__ dist,
                      const int*   __restrict__ mask,
                      const float* __restrict__ table,   // [101][32] f32
                      const float* __restrict__ w_in,    // [65][256] f32 (row 64 used)
                      const float* __restrict__ b_in,
                      const float* __restrict__ b_a1,
                      const float* __restrict__ w_a2,
                      const float* __restrict__ b_a2,
                      const float* __restrict__ b_v1,
                      const float* __restrict__ b_v2,
                      const float* __restrict__ fb,
                      const unsigned short* __restrict__ ws,
                      float*       __restrict__ out) {
    // sU: P0-P1: comb B-frags (8192B). P2+: scorep @0 (1KB) | attn @1024 ([4][64] f32) | r_bf @2048 (512B)
    __shared__ __align__(16) unsigned char sU[8192];
    // hidfrag[dt][kt][lane][j] = hid[d=16dt+(lane&15)][h=kt*32 + 16*(j>>2)+4*(lane>>4)+(j&3)]
    __shared__ __align__(16) unsigned short hidfrag[4][8][64][8];  // 32768B; total 40960B

    unsigned short (*combfrag)[2][64][8] = (unsigned short (*)[2][64][8])sU;
    float*          scorep = (float*)sU;               // [4][64]
    float*          attn_s = (float*)(sU + 1024);      // [4][64] per-wave copies
    unsigned short* r_bf   = (unsigned short*)(sU + 2048);  // [256] bf16

    const int tid = threadIdx.x;
    const int l   = tid & 63;
    const int w   = tid >> 6;
    const int g   = l >> 4;
    const int li  = l & 15;
    const int blk = blockIdx.x;
    const long base = (long)blk * DD;

    // ---- P0: wave w builds comb B-frag tile dt=w (pairs d = 16w+li) ----
    {
        const int i1 = a1[base + 16 * w + li];
        const int i2 = a2[base + 16 * w + li];
        #pragma unroll
        for (int ks = 0; ks < 2; ++ks) {
            const int idx = ks ? i2 : i1;
            const float* srcp = table + (size_t)idx * 32 + 8 * g;
            f32x4 v0 = *(const f32x4*)srcp;
            f32x4 v1 = *(const f32x4*)(srcp + 4);
            u16x8 u;
            #pragma unroll
            for (int j = 0; j < 4; ++j) { u[j] = to_bf16u(v0[j]); u[j + 4] = to_bf16u(v1[j]); }
            *(u16x8*)&combfrag[w][ks][l][0] = u;
        }
    }
    __syncthreads();

    // ---- P1: hidT = w_inT @ combT (+ dm*w64 + b_in), gelu -> hidfrag (register-native A-frags) ----
    {
        bf16x8 cb[4][2];
        #pragma unroll
        for (int dt = 0; dt < 4; ++dt)
            #pragma unroll
            for (int ks = 0; ks < 2; ++ks)
                cb[dt][ks] = *(const bf16x8*)&combfrag[dt][ks][l][0];
        float dmv[4];
        #pragma unroll
        for (int dt = 0; dt < 4; ++dt) {
            int m = mask[base + 16 * dt + li];
            dmv[dt] = m ? dist[base + 16 * dt + li] : 0.0f;
        }
        #pragma unroll
        for (int hp = 0; hp < 2; ++hp) {          // own k-tile: kt = 2w+hp
            u16x8 pend[4];
            #pragma unroll
            for (int b = 0; b < 2; ++b) {
                const int ht = 4 * w + 2 * hp + b;
                bf16x8 af0 = *(const bf16x8*)(ws + WIN_OFF + ((0 * 16 + ht) * 64 + l) * 8);
                bf16x8 af1 = *(const bf16x8*)(ws + WIN_OFF + ((1 * 16 + ht) * 64 + l) * 8);
                f32x4 w64v = *(const f32x4*)&w_in[64 * 256 + 16 * ht + 4 * g];
                f32x4 binv = *(const f32x4*)&b_in[16 * ht + 4 * g];
                #pragma unroll
                for (int dt = 0; dt < 4; ++dt) {
                    f32x4 acc = {0.f, 0.f, 0.f, 0.f};
                    acc = mfma16(af0, cb[dt][0], acc);
                    acc = mfma16(af1, cb[dt][1], acc);
                    #pragma unroll
                    for (int p = 0; p < 4; ++p) {
                        float h = gelu_fast(acc[p] + dmv[dt] * w64v[p] + binv[p]);
                        pend[dt][4 * b + p] = to_bf16u(h);
                    }
                }
            }
            #pragma unroll
            for (int dt = 0; dt < 4; ++dt)
                *(u16x8*)&hidfrag[dt][2 * w + hp][l][0] = pend[dt];
        }
    }
    __syncthreads();

    // ---- P2: score partials (wave w -> attn-hidden cols 16w..16w+15) ----
    {
        const float ba1 = b_a1[16 * w + li];
        const float wa2 = w_a2[16 * w + li];
        f32x4 acc[4];
        #pragma unroll
        for (int rt = 0; rt < 4; ++rt) acc[rt] = (f32x4){0.f, 0.f, 0.f, 0.f};
        #pragma unroll
        for (int kt = 0; kt < 8; ++kt) {
            bf16x8 b = *(const bf16x8*)(ws + WA1_OFF + ((kt * 4 + w) * 64 + l) * 8);
            #pragma unroll
            for (int rt = 0; rt < 4; ++rt) {
                bf16x8 a = *(const bf16x8*)&hidfrag[rt][kt][l][0];
                acc[rt] = mfma16(a, b, acc[rt]);
            }
        }
        #pragma unroll
        for (int rt = 0; rt < 4; ++rt) {
            float s[4];
            #pragma unroll
            for (int p = 0; p < 4; ++p) s[p] = gelu_fast(acc[rt][p] + ba1) * wa2;
            #pragma unroll
            for (int off = 1; off <= 8; off <<= 1)
                #pragma unroll
                for (int p = 0; p < 4; ++p) s[p] += __shfl_xor(s[p], off, 64);
            if (li == 0) {
                f32x4 sv; sv[0] = s[0]; sv[1] = s[1]; sv[2] = s[2]; sv[3] = s[3];
                *(f32x4*)&scorep[w * 64 + 16 * rt + 4 * g] = sv;
            }
        }
    }
    __syncthreads();

    // ---- P3: softmax, redundant per wave (no extra barrier) ----
    {
        const int m = mask[base + l];
        float sc = scorep[l] + scorep[64 + l] + scorep[128 + l] + scorep[192 + l] + b_a2[0];
        if (!m) sc = -10000.0f;
        float mx = sc;
        #pragma unroll
        for (int off = 32; off; off >>= 1) mx = fmaxf(mx, __shfl_xor(mx, off, 64));
        float p = __expf(sc - mx);
        float sm = p;
        #pragma unroll
        for (int off = 32; off; off >>= 1) sm += __shfl_xor(sm, off, 64);
        attn_s[w * 64 + l] = p / sm;
    }
    // same-wave LDS RAW -> ordered by lgkmcnt, no __syncthreads needed

    // ---- P4: r[c] = sum_d attn[d]*gelu(hid@w_v1 + b_v1)[d][c]  (wave w -> cols 64w..) ----
    // ct processed in 2 passes of 2 to cap live accumulators at 32 (de-spill).
    {
        f32x4 av[4];
        #pragma unroll
        for (int rt = 0; rt < 4; ++rt) av[rt] = *(const f32x4*)&attn_s[w * 64 + 16 * rt + 4 * g];
        #pragma unroll
        for (int half = 0; half < 2; ++half) {
            f32x4 acc3[2][4];   // [c2][rt]
            #pragma unroll
            for (int c2 = 0; c2 < 2; ++c2)
                #pragma unroll
                for (int rt = 0; rt < 4; ++rt) acc3[c2][rt] = (f32x4){0.f, 0.f, 0.f, 0.f};
            #pragma unroll
            for (int kt = 0; kt < 8; ++kt) {
                bf16x8 a[4];
                #pragma unroll
                for (int rt = 0; rt < 4; ++rt) a[rt] = *(const bf16x8*)&hidfrag[rt][kt][l][0];
                #pragma unroll
                for (int c2 = 0; c2 < 2; ++c2) {
                    const int ct = 2 * half + c2;
                    bf16x8 b = *(const bf16x8*)(ws + WV1_OFF + ((kt * 16 + 4 * w + ct) * 64 + l) * 8);
                    #pragma unroll
                    for (int rt = 0; rt < 4; ++rt) acc3[c2][rt] = mfma16(a[rt], b, acc3[c2][rt]);
                }
            }
            #pragma unroll
            for (int c2 = 0; c2 < 2; ++c2) {
                const int ct = 2 * half + c2;
                const int c = 64 * w + 16 * ct + li;
                const float bv = b_v1[c];
                float val = 0.f;
                #pragma unroll
                for (int rt = 0; rt < 4; ++rt)
                    #pragma unroll
                    for (int p = 0; p < 4; ++p)
                        val += av[rt][p] * gelu_fast(acc3[c2][rt][p] + bv);
                val += __shfl_xor(val, 16, 64);
                val += __shfl_xor(val, 32, 64);
                if (g == 0) r_bf[c] = to_bf16u(val);
            }
        }
    }
    __syncthreads();

    // ---- P5: out = r @ w_v2 via MFMA (r broadcast to all 16 A-rows), full K per wave ----
    {
        const int anyv = __any(mask[base + l] != 0);   // recomputed (no long live range)
        f32x4 acc[4];
        #pragma unroll
        for (int ct = 0; ct < 4; ++ct) acc[ct] = (f32x4){0.f, 0.f, 0.f, 0.f};
        #pragma unroll
        for (int kt = 0; kt < 8; ++kt) {
            bf16x8 a = *(const bf16x8*)&r_bf[kt * 32 + 8 * g];   // same for all li -> broadcast
            #pragma unroll
            for (int ct = 0; ct < 4; ++ct) {
                bf16x8 b = *(const bf16x8*)(ws + WV2_OFF + ((kt * 16 + 4 * w + ct) * 64 + l) * 8);
                acc[ct] = mfma16(a, b, acc[ct]);
            }
        }
        if (g == 0) {
            #pragma unroll
            for (int ct = 0; ct < 4; ++ct) {
                const int c = 16 * (4 * w + ct) + li;
                float o = acc[ct][0] + b_v2[c];
                if (!anyv) o = fb[c];
                out[(size_t)blk * HH + c] = o;
            }
        }
    }
}

extern "C" void kernel_launch(void* const* d_in, const int* in_sizes, int n_in,
                              void* d_out, int out_size, void* d_ws, size_t ws_size,
                              hipStream_t stream) {
    const int*   a1    = (const int*)  d_in[0];
    const int*   a2    = (const int*)  d_in[1];
    const float* dist  = (const float*)d_in[2];
    const int*   mask  = (const int*)  d_in[3];
    const float* table = (const float*)d_in[4];
    const float* w_in  = (const float*)d_in[5];
    const float* b_in  = (const float*)d_in[6];
    const float* w_a1  = (const float*)d_in[7];
    const float* b_a1  = (const float*)d_in[8];
    const float* w_a2  = (const float*)d_in[9];
    const float* b_a2  = (const float*)d_in[10];
    const float* w_v1  = (const float*)d_in[11];
    const float* b_v1  = (const float*)d_in[12];
    const float* w_v2  = (const float*)d_in[13];
    const float* b_v2  = (const float*)d_in[14];
    const float* fb    = (const float*)d_in[15];
    float* out = (float*)d_out;
    unsigned short* ws = (unsigned short*)d_ws;

    pack_weights<<<80, 256, 0, stream>>>(w_in, w_a1, w_v1, w_v2, ws);
    dist_attn_kernel<<<BW, 256, 0, stream>>>(a1, a2, dist, mask, table,
                                             w_in, b_in, b_a1, w_a2, b_a2,
                                             b_v1, b_v2, fb, ws, out);
}